// Round 3
// baseline (260.123 us; speedup 1.0000x reference)
//
#include <hip/hip_runtime.h>

#define L_MAX 16
#define MARGIN 0.4f
#define EPS 1e-8f
#define NSENT 64

// ---------- fused counting sort: histogram + scan + scatter, one block ----------
__global__ __launch_bounds__(256) void sort_pairs_kernel(
    const int* __restrict__ sid, int* __restrict__ perm, int N)
{
    __shared__ int h[NSENT];
    const int t = (int)threadIdx.x;
    if (t < NSENT) h[t] = 0;
    __syncthreads();
    for (int i = t; i < N; i += 256)
        atomicAdd(&h[sid[i]], 1);
    __syncthreads();
    if (t == 0) {                       // 64-bin serial exclusive scan: trivial
        int acc = 0;
        for (int b = 0; b < NSENT; ++b) { int c = h[b]; h[b] = acc; acc += c; }
    }
    __syncthreads();
    for (int i = t; i < N; i += 256) {
        const int p = atomicAdd(&h[sid[i]], 1);
        perm[p] = i;                    // order within a sentence is arbitrary;
    }                                   // output is indexed by original pid -> deterministic
}

// ---------- main: one wave per pair, sid-grouped + XCD-swizzled ----------
// Clamped-index max-pool: row j reads st + min(j, len) for j = 0..15.
// Identical result (duplicate rows are fmax no-ops), always in bounds
// (start < S - L_MAX), and the compile-time trip count lets ALL row loads
// be issued address-independently -> latency-bound becomes throughput-bound.
__global__ __launch_bounds__(256) void span_pair_loss_kernel(
    const float* __restrict__ emb,
    const int*   __restrict__ sid,
    const int*   __restrict__ s_start,
    const int*   __restrict__ s_len,
    const int*   __restrict__ t_start,
    const int*   __restrict__ t_len,
    const int*   __restrict__ labels,
    const int*   __restrict__ perm,
    float*       __restrict__ loss_out,
    int N, int S, int D)
{
    // bijective XCD swizzle (m204): give each XCD a CONTIGUOUS chunk of the
    // sid-sorted pair list -> concurrent working set per XCD ~2 sentences
    // = 4 MiB = one XCD L2.
    const int orig = (int)blockIdx.x;
    const int nwg  = (int)gridDim.x;
    const int q = nwg >> 3, r = nwg & 7;
    const int x = orig & 7, j0 = orig >> 3;
    const int swz = (x < r ? x * (q + 1) : r * (q + 1) + (x - r) * q) + j0;

    const int lane  = (int)(threadIdx.x & 63);
    const int pslot = swz * 4 + (int)(threadIdx.x >> 6);
    if (pslot >= N) return;
    const int pid = perm[pslot];

    const int b  = sid[pid];
    const int ss = s_start[pid];
    const int ls = s_len[pid];
    const int ts = t_start[pid];
    const int lt = t_len[pid];

    const float* __restrict__ base = emb + (size_t)b * (size_t)S * (size_t)D;
    const int D4 = D >> 2;              // 256 float4 per row
    const float4* __restrict__ sbase = reinterpret_cast<const float4*>(base + (size_t)ss * D);
    const float4* __restrict__ tbase = reinterpret_cast<const float4*>(base + (size_t)ts * D);

    float4 sm[4], tm[4];
    #pragma unroll
    for (int k = 0; k < 4; ++k) sm[k] = sbase[k * 64 + lane];
    #pragma unroll
    for (int k = 0; k < 4; ++k) tm[k] = tbase[k * 64 + lane];

    #pragma unroll
    for (int j = 1; j < L_MAX; ++j) {
        const int js = min(j, ls);      // clamp: dup rows are fmax no-ops
        const int jt = min(j, lt);
        const float4* __restrict__ sr = sbase + (size_t)js * D4;
        const float4* __restrict__ tr = tbase + (size_t)jt * D4;
        float4 a[4], c[4];
        #pragma unroll
        for (int k = 0; k < 4; ++k) a[k] = sr[k * 64 + lane];
        #pragma unroll
        for (int k = 0; k < 4; ++k) c[k] = tr[k * 64 + lane];
        #pragma unroll
        for (int k = 0; k < 4; ++k) {
            sm[k].x = fmaxf(sm[k].x, a[k].x); sm[k].y = fmaxf(sm[k].y, a[k].y);
            sm[k].z = fmaxf(sm[k].z, a[k].z); sm[k].w = fmaxf(sm[k].w, a[k].w);
            tm[k].x = fmaxf(tm[k].x, c[k].x); tm[k].y = fmaxf(tm[k].y, c[k].y);
            tm[k].z = fmaxf(tm[k].z, c[k].z); tm[k].w = fmaxf(tm[k].w, c[k].w);
        }
    }

    float dot = 0.f, ssq = 0.f, tsq = 0.f;
    #pragma unroll
    for (int k = 0; k < 4; ++k) {
        dot += sm[k].x * tm[k].x + sm[k].y * tm[k].y + sm[k].z * tm[k].z + sm[k].w * tm[k].w;
        ssq += sm[k].x * sm[k].x + sm[k].y * sm[k].y + sm[k].z * sm[k].z + sm[k].w * sm[k].w;
        tsq += tm[k].x * tm[k].x + tm[k].y * tm[k].y + tm[k].z * tm[k].z + tm[k].w * tm[k].w;
    }

    #pragma unroll
    for (int off = 32; off > 0; off >>= 1) {
        dot += __shfl_down(dot, off, 64);
        ssq += __shfl_down(ssq, off, 64);
        tsq += __shfl_down(tsq, off, 64);
    }

    if (lane == 0) {
        const float cosv = dot / (sqrtf(ssq) * sqrtf(tsq) + EPS);
        const float l = (labels[pid] > 0) ? (1.0f - cosv)
                                          : fmaxf(0.0f, cosv - MARGIN);
        loss_out[pid] = l;
    }
}

// ---------- deterministic mean ----------
__global__ __launch_bounds__(256) void mean_reduce_kernel(
    const float* __restrict__ loss, float* __restrict__ out, int N)
{
    float sum = 0.f;
    for (int i = (int)threadIdx.x; i < N; i += 256)
        sum += loss[i];
    #pragma unroll
    for (int off = 32; off > 0; off >>= 1)
        sum += __shfl_down(sum, off, 64);

    __shared__ float sdata[4];
    const int w = (int)(threadIdx.x >> 6);
    if ((threadIdx.x & 63) == 0) sdata[w] = sum;
    __syncthreads();
    if (threadIdx.x == 0)
        out[0] = (sdata[0] + sdata[1] + sdata[2] + sdata[3]) / (float)N;
}

extern "C" void kernel_launch(void* const* d_in, const int* in_sizes, int n_in,
                              void* d_out, int out_size, void* d_ws, size_t ws_size,
                              hipStream_t stream) {
    const float* emb     = (const float*)d_in[0];
    const int*   sid     = (const int*)d_in[1];
    const int*   s_start = (const int*)d_in[2];
    const int*   s_len   = (const int*)d_in[3];
    const int*   t_start = (const int*)d_in[4];
    const int*   t_len   = (const int*)d_in[5];
    const int*   labels  = (const int*)d_in[6];

    const int N = in_sizes[1];          // 8192 pairs
    const int S = 512;
    const int D = 1024;

    // workspace layout: [N floats loss][N ints perm]
    float* loss_ws = (float*)d_ws;
    int*   perm    = (int*)((char*)d_ws + (size_t)N * 4);

    sort_pairs_kernel<<<1, 256, 0, stream>>>(sid, perm, N);

    const int blocks = (N + 3) / 4;     // 4 waves (pairs) per 256-thread block
    span_pair_loss_kernel<<<blocks, 256, 0, stream>>>(
        emb, sid, s_start, s_len, t_start, t_len, labels, perm, loss_ws, N, S, D);

    mean_reduce_kernel<<<1, 256, 0, stream>>>(loss_ws, (float*)d_out, N);
}

// Round 9
// 244.861 us; speedup vs baseline: 1.0623x; 1.0623x over previous
//
#include <hip/hip_runtime.h>

#define L_MAX 16
#define MARGIN 0.4f
#define EPS 1e-8f
#define NSENT 64

// ---------- fused counting sort: histogram + scan + scatter, one block ----------
__global__ __launch_bounds__(256) void sort_pairs_kernel(
    const int* __restrict__ sid, int* __restrict__ perm, int N)
{
    __shared__ int h[NSENT];
    const int t = (int)threadIdx.x;
    if (t < NSENT) h[t] = 0;
    __syncthreads();
    for (int i = t; i < N; i += 256)
        atomicAdd(&h[sid[i]], 1);
    __syncthreads();
    if (t == 0) {                       // 64-bin serial exclusive scan: trivial
        int acc = 0;
        for (int b = 0; b < NSENT; ++b) { int c = h[b]; h[b] = acc; acc += c; }
    }
    __syncthreads();
    for (int i = t; i < N; i += 256) {
        const int p = atomicAdd(&h[sid[i]], 1);
        perm[p] = i;                    // order within a sentence arbitrary;
    }                                   // output indexed by original pid -> deterministic
}

// ---------- main: one wave per pair, sid-grouped + XCD-swizzled ----------
// Exact-length predicated loops: len is wave-uniform, so the `if (j <= len)`
// guards are uniform branches (no lane divergence). All row addresses depend
// only on inputs -> loads are address-independent; avg traffic ~19 rows/pair
// instead of the clamped version's 32 (we are L1-return-BW bound, so
// duplicate loads cost full price).
__global__ __launch_bounds__(256) void span_pair_loss_kernel(
    const float* __restrict__ emb,
    const int*   __restrict__ sid,
    const int*   __restrict__ s_start,
    const int*   __restrict__ s_len,
    const int*   __restrict__ t_start,
    const int*   __restrict__ t_len,
    const int*   __restrict__ labels,
    const int*   __restrict__ perm,
    float*       __restrict__ loss_out,
    int N, int S, int D)
{
    // bijective XCD swizzle (m204): each XCD walks a CONTIGUOUS chunk of the
    // sid-sorted pair list -> working set ~2 sentences = 4 MiB = one XCD L2.
    const int orig = (int)blockIdx.x;
    const int nwg  = (int)gridDim.x;
    const int q = nwg >> 3, r = nwg & 7;
    const int x = orig & 7, j0 = orig >> 3;
    const int swz = (x < r ? x * (q + 1) : r * (q + 1) + (x - r) * q) + j0;

    const int lane  = (int)(threadIdx.x & 63);
    const int pslot = swz * 4 + (int)(threadIdx.x >> 6);
    if (pslot >= N) return;
    const int pid = perm[pslot];

    const int b  = sid[pid];
    const int ss = s_start[pid];
    const int ls = s_len[pid];
    const int ts = t_start[pid];
    const int lt = t_len[pid];

    const float* __restrict__ base = emb + (size_t)b * (size_t)S * (size_t)D;
    const int D4 = D >> 2;              // 256 float4 per row
    const float4* __restrict__ sbase = reinterpret_cast<const float4*>(base + (size_t)ss * D);
    const float4* __restrict__ tbase = reinterpret_cast<const float4*>(base + (size_t)ts * D);

    float4 sm[4], tm[4];
    #pragma unroll
    for (int k = 0; k < 4; ++k) sm[k] = sbase[k * 64 + lane];
    #pragma unroll
    for (int k = 0; k < 4; ++k) tm[k] = tbase[k * 64 + lane];

    const int lmax = max(ls, lt);
    #pragma unroll 4
    for (int j = 1; j <= lmax; ++j) {   // wave-uniform trip count
        float4 a[4], c[4];
        const bool ds = (j <= ls), dt = (j <= lt);
        if (ds) {
            #pragma unroll
            for (int k = 0; k < 4; ++k) a[k] = sbase[(size_t)j * D4 + k * 64 + lane];
        }
        if (dt) {
            #pragma unroll
            for (int k = 0; k < 4; ++k) c[k] = tbase[(size_t)j * D4 + k * 64 + lane];
        }
        if (ds) {
            #pragma unroll
            for (int k = 0; k < 4; ++k) {
                sm[k].x = fmaxf(sm[k].x, a[k].x); sm[k].y = fmaxf(sm[k].y, a[k].y);
                sm[k].z = fmaxf(sm[k].z, a[k].z); sm[k].w = fmaxf(sm[k].w, a[k].w);
            }
        }
        if (dt) {
            #pragma unroll
            for (int k = 0; k < 4; ++k) {
                tm[k].x = fmaxf(tm[k].x, c[k].x); tm[k].y = fmaxf(tm[k].y, c[k].y);
                tm[k].z = fmaxf(tm[k].z, c[k].z); tm[k].w = fmaxf(tm[k].w, c[k].w);
            }
        }
    }

    float dot = 0.f, ssq = 0.f, tsq = 0.f;
    #pragma unroll
    for (int k = 0; k < 4; ++k) {
        dot += sm[k].x * tm[k].x + sm[k].y * tm[k].y + sm[k].z * tm[k].z + sm[k].w * tm[k].w;
        ssq += sm[k].x * sm[k].x + sm[k].y * sm[k].y + sm[k].z * sm[k].z + sm[k].w * sm[k].w;
        tsq += tm[k].x * tm[k].x + tm[k].y * tm[k].y + tm[k].z * tm[k].z + tm[k].w * tm[k].w;
    }

    #pragma unroll
    for (int off = 32; off > 0; off >>= 1) {
        dot += __shfl_down(dot, off, 64);
        ssq += __shfl_down(ssq, off, 64);
        tsq += __shfl_down(tsq, off, 64);
    }

    if (lane == 0) {
        const float cosv = dot / (sqrtf(ssq) * sqrtf(tsq) + EPS);
        const float l = (labels[pid] > 0) ? (1.0f - cosv)
                                          : fmaxf(0.0f, cosv - MARGIN);
        loss_out[pid] = l;
    }
}

// ---------- deterministic mean ----------
__global__ __launch_bounds__(256) void mean_reduce_kernel(
    const float* __restrict__ loss, float* __restrict__ out, int N)
{
    float sum = 0.f;
    for (int i = (int)threadIdx.x; i < N; i += 256)
        sum += loss[i];
    #pragma unroll
    for (int off = 32; off > 0; off >>= 1)
        sum += __shfl_down(sum, off, 64);

    __shared__ float sdata[4];
    const int w = (int)(threadIdx.x >> 6);
    if ((threadIdx.x & 63) == 0) sdata[w] = sum;
    __syncthreads();
    if (threadIdx.x == 0)
        out[0] = (sdata[0] + sdata[1] + sdata[2] + sdata[3]) / (float)N;
}

extern "C" void kernel_launch(void* const* d_in, const int* in_sizes, int n_in,
                              void* d_out, int out_size, void* d_ws, size_t ws_size,
                              hipStream_t stream) {
    const float* emb     = (const float*)d_in[0];
    const int*   sid     = (const int*)d_in[1];
    const int*   s_start = (const int*)d_in[2];
    const int*   s_len   = (const int*)d_in[3];
    const int*   t_start = (const int*)d_in[4];
    const int*   t_len   = (const int*)d_in[5];
    const int*   labels  = (const int*)d_in[6];

    const int N = in_sizes[1];          // 8192 pairs
    const int S = 512;
    const int D = 1024;

    // workspace layout: [N floats loss][N ints perm]
    float* loss_ws = (float*)d_ws;
    int*   perm    = (int*)((char*)d_ws + (size_t)N * 4);

    sort_pairs_kernel<<<1, 256, 0, stream>>>(sid, perm, N);

    const int blocks = (N + 3) / 4;     // 4 waves (pairs) per 256-thread block
    span_pair_loss_kernel<<<blocks, 256, 0, stream>>>(
        emb, sid, s_start, s_len, t_start, t_len, labels, perm, loss_ws, N, S, D);

    mean_reduce_kernel<<<1, 256, 0, stream>>>(loss_ws, (float*)d_out, N);
}

// Round 11
// 241.210 us; speedup vs baseline: 1.0784x; 1.0151x over previous
//
#include <hip/hip_runtime.h>

#define L_MAX 16
#define MARGIN 0.4f
#define EPS 1e-8f
#define NSENT 64

// ---------- fused counting sort: histogram + scan + scatter, one block ----------
__global__ __launch_bounds__(256) void sort_pairs_kernel(
    const int* __restrict__ sid, int* __restrict__ perm, int N)
{
    __shared__ int h[NSENT];
    const int t = (int)threadIdx.x;
    if (t < NSENT) h[t] = 0;
    __syncthreads();
    for (int i = t; i < N; i += 256)
        atomicAdd(&h[sid[i]], 1);
    __syncthreads();
    if (t == 0) {                       // 64-bin serial exclusive scan: trivial
        int acc = 0;
        for (int b = 0; b < NSENT; ++b) { int c = h[b]; h[b] = acc; acc += c; }
    }
    __syncthreads();
    for (int i = t; i < N; i += 256) {
        const int p = atomicAdd(&h[sid[i]], 1);
        perm[p] = i;                    // order within a sentence arbitrary;
    }                                   // output indexed by original pid -> deterministic
}

// ---------- main: one wave per pair, sid-grouped + XCD-swizzled ----------
// 2-row chunks with tail-clamp: rows min(2c+1,len), min(2c+2,len) for
// c < ceil(len/2). Only the last chunk can duplicate a row (fmax no-op),
// avg +0.5 rows/span (~3% traffic) -- vs full clamp's +68%. All 4 row-loads
// per chunk (2 s + 2 t) are unguarded within uniform ifs -> 256 B/lane of
// address-independent loads batch per iteration (2x the exact-length
// version's MLP, whose loop-exit branches blocked load speculation).
__global__ __launch_bounds__(256) void span_pair_loss_kernel(
    const float* __restrict__ emb,
    const int*   __restrict__ sid,
    const int*   __restrict__ s_start,
    const int*   __restrict__ s_len,
    const int*   __restrict__ t_start,
    const int*   __restrict__ t_len,
    const int*   __restrict__ labels,
    const int*   __restrict__ perm,
    float*       __restrict__ loss_out,
    int N, int S, int D)
{
    // bijective XCD swizzle (m204): each XCD walks a CONTIGUOUS chunk of the
    // sid-sorted pair list -> working set ~2 sentences = 4 MiB = one XCD L2.
    const int orig = (int)blockIdx.x;
    const int nwg  = (int)gridDim.x;
    const int q = nwg >> 3, r = nwg & 7;
    const int x = orig & 7, j0 = orig >> 3;
    const int swz = (x < r ? x * (q + 1) : r * (q + 1) + (x - r) * q) + j0;

    const int lane  = (int)(threadIdx.x & 63);
    const int pslot = swz * 4 + (int)(threadIdx.x >> 6);
    if (pslot >= N) return;
    const int pid = perm[pslot];

    const int b  = sid[pid];
    const int ss = s_start[pid];
    const int ls = s_len[pid];
    const int ts = t_start[pid];
    const int lt = t_len[pid];

    const float* __restrict__ base = emb + (size_t)b * (size_t)S * (size_t)D;
    const int D4 = D >> 2;              // 256 float4 per row
    const float4* __restrict__ sbase = reinterpret_cast<const float4*>(base + (size_t)ss * D);
    const float4* __restrict__ tbase = reinterpret_cast<const float4*>(base + (size_t)ts * D);

    float4 sm[4], tm[4];
    #pragma unroll
    for (int k = 0; k < 4; ++k) sm[k] = sbase[k * 64 + lane];
    #pragma unroll
    for (int k = 0; k < 4; ++k) tm[k] = tbase[k * 64 + lane];

    const int cs = (ls + 1) >> 1;       // chunks for s (0..8)
    const int ct = (lt + 1) >> 1;       // chunks for t
    const int cmax = max(cs, ct);

    for (int c = 0; c < cmax; ++c) {    // wave-uniform trip count
        const bool ds = (c < cs), dt = (c < ct);
        float4 a0[4], a1[4], b0[4], b1[4];
        if (ds) {
            const int j1 = min(2 * c + 1, ls);
            const int j2 = min(2 * c + 2, ls);
            const float4* __restrict__ r1 = sbase + (size_t)j1 * D4;
            const float4* __restrict__ r2 = sbase + (size_t)j2 * D4;
            #pragma unroll
            for (int k = 0; k < 4; ++k) { a0[k] = r1[k * 64 + lane]; a1[k] = r2[k * 64 + lane]; }
        }
        if (dt) {
            const int j1 = min(2 * c + 1, lt);
            const int j2 = min(2 * c + 2, lt);
            const float4* __restrict__ r1 = tbase + (size_t)j1 * D4;
            const float4* __restrict__ r2 = tbase + (size_t)j2 * D4;
            #pragma unroll
            for (int k = 0; k < 4; ++k) { b0[k] = r1[k * 64 + lane]; b1[k] = r2[k * 64 + lane]; }
        }
        if (ds) {
            #pragma unroll
            for (int k = 0; k < 4; ++k) {
                sm[k].x = fmaxf(sm[k].x, fmaxf(a0[k].x, a1[k].x));
                sm[k].y = fmaxf(sm[k].y, fmaxf(a0[k].y, a1[k].y));
                sm[k].z = fmaxf(sm[k].z, fmaxf(a0[k].z, a1[k].z));
                sm[k].w = fmaxf(sm[k].w, fmaxf(a0[k].w, a1[k].w));
            }
        }
        if (dt) {
            #pragma unroll
            for (int k = 0; k < 4; ++k) {
                tm[k].x = fmaxf(tm[k].x, fmaxf(b0[k].x, b1[k].x));
                tm[k].y = fmaxf(tm[k].y, fmaxf(b0[k].y, b1[k].y));
                tm[k].z = fmaxf(tm[k].z, fmaxf(b0[k].z, b1[k].z));
                tm[k].w = fmaxf(tm[k].w, fmaxf(b0[k].w, b1[k].w));
            }
        }
    }

    float dot = 0.f, ssq = 0.f, tsq = 0.f;
    #pragma unroll
    for (int k = 0; k < 4; ++k) {
        dot += sm[k].x * tm[k].x + sm[k].y * tm[k].y + sm[k].z * tm[k].z + sm[k].w * tm[k].w;
        ssq += sm[k].x * sm[k].x + sm[k].y * sm[k].y + sm[k].z * sm[k].z + sm[k].w * sm[k].w;
        tsq += tm[k].x * tm[k].x + tm[k].y * tm[k].y + tm[k].z * tm[k].z + tm[k].w * tm[k].w;
    }

    #pragma unroll
    for (int off = 32; off > 0; off >>= 1) {
        dot += __shfl_down(dot, off, 64);
        ssq += __shfl_down(ssq, off, 64);
        tsq += __shfl_down(tsq, off, 64);
    }

    if (lane == 0) {
        const float cosv = dot / (sqrtf(ssq) * sqrtf(tsq) + EPS);
        const float l = (labels[pid] > 0) ? (1.0f - cosv)
                                          : fmaxf(0.0f, cosv - MARGIN);
        loss_out[pid] = l;
    }
}

// ---------- deterministic mean ----------
__global__ __launch_bounds__(256) void mean_reduce_kernel(
    const float* __restrict__ loss, float* __restrict__ out, int N)
{
    float sum = 0.f;
    for (int i = (int)threadIdx.x; i < N; i += 256)
        sum += loss[i];
    #pragma unroll
    for (int off = 32; off > 0; off >>= 1)
        sum += __shfl_down(sum, off, 64);

    __shared__ float sdata[4];
    const int w = (int)(threadIdx.x >> 6);
    if ((threadIdx.x & 63) == 0) sdata[w] = sum;
    __syncthreads();
    if (threadIdx.x == 0)
        out[0] = (sdata[0] + sdata[1] + sdata[2] + sdata[3]) / (float)N;
}

extern "C" void kernel_launch(void* const* d_in, const int* in_sizes, int n_in,
                              void* d_out, int out_size, void* d_ws, size_t ws_size,
                              hipStream_t stream) {
    const float* emb     = (const float*)d_in[0];
    const int*   sid     = (const int*)d_in[1];
    const int*   s_start = (const int*)d_in[2];
    const int*   s_len   = (const int*)d_in[3];
    const int*   t_start = (const int*)d_in[4];
    const int*   t_len   = (const int*)d_in[5];
    const int*   labels  = (const int*)d_in[6];

    const int N = in_sizes[1];          // 8192 pairs
    const int S = 512;
    const int D = 1024;

    // workspace layout: [N floats loss][N ints perm]
    float* loss_ws = (float*)d_ws;
    int*   perm    = (int*)((char*)d_ws + (size_t)N * 4);

    sort_pairs_kernel<<<1, 256, 0, stream>>>(sid, perm, N);

    const int blocks = (N + 3) / 4;     // 4 waves (pairs) per 256-thread block
    span_pair_loss_kernel<<<blocks, 256, 0, stream>>>(
        emb, sid, s_start, s_len, t_start, t_len, labels, perm, loss_ws, N, S, D);

    mean_reduce_kernel<<<1, 256, 0, stream>>>(loss_ws, (float*)d_out, N);
}